// Round 1
// 774.383 us; speedup vs baseline: 1.0520x; 1.0520x over previous
//
#include <hip/hip_runtime.h>

#define NUM_CLASSES 100000
#define NUM_FEATURES 256
#define BATCH 1024
#define SCALARF 30.0f
#define EPSF 1e-12f

typedef __attribute__((ext_vector_type(4))) float float4v;
typedef __attribute__((ext_vector_type(8))) short short8;   // 8 x bf16 (4 VGPRs)
typedef __attribute__((ext_vector_type(4))) short short4v;  // 4 x bf16 (8 B)

static __device__ inline short f2bf(float f) {
    // round-to-nearest-even fp32 -> bf16 (inputs are finite randn; NaN path irrelevant)
    unsigned u = __builtin_bit_cast(unsigned, f);
    unsigned r = (u + 0x7FFFu + ((u >> 16) & 1u)) >> 16;
    return (short)r;
}

static __device__ inline float wave_reduce_sum(float s) {
#pragma unroll
    for (int off = 32; off > 0; off >>= 1) s += __shfl_xor(s, off, 64);
    return s;
}

// ---------------------------------------------------------------------------
// K1: normalize x rows -> xn (fp32) and xnb (bf16); echo targets as float32.
// One wave per row; lane holds 4 contiguous floats.
__global__ __launch_bounds__(64) void xnorm_kernel(const float* __restrict__ x,
                                                   const int* __restrict__ tgt,
                                                   float* __restrict__ xn,
                                                   short* __restrict__ xnb,
                                                   float* __restrict__ out_tgt) {
    int row = blockIdx.x;
    int lane = threadIdx.x;
    const float4v v = *(const float4v*)(x + (size_t)row * NUM_FEATURES + lane * 4);
    float s = v.x * v.x + v.y * v.y + v.z * v.z + v.w * v.w;
    s = wave_reduce_sum(s);
    float scale = 1.0f / fmaxf(sqrtf(s), EPSF);
    float4v nv = v * scale;
    *(float4v*)(xn + (size_t)row * NUM_FEATURES + lane * 4) = nv;
    short4v bv;
    bv.x = f2bf(nv.x); bv.y = f2bf(nv.y); bv.z = f2bf(nv.z); bv.w = f2bf(nv.w);
    *(short4v*)(xnb + (size_t)row * NUM_FEATURES + lane * 4) = bv;
    if (lane == 0) out_tgt[row] = (float)tgt[row];
}

// ---------------------------------------------------------------------------
// K2: per weight row: copy raw row -> out_w (new_weight baseline), and write
// normalized bf16 row -> wnb (GEMM B operand). 4 waves/block, 1 row/wave.
__global__ __launch_bounds__(256) void wnorm_kernel(const float* __restrict__ w,
                                                    short* __restrict__ wnb,
                                                    float* __restrict__ out_w) {
    int row = blockIdx.x * 4 + (threadIdx.x >> 6);
    int lane = threadIdx.x & 63;
    const float4v v = *(const float4v*)(w + (size_t)row * NUM_FEATURES + lane * 4);
    float s = v.x * v.x + v.y * v.y + v.z * v.z + v.w * v.w;
    s = wave_reduce_sum(s);
    float scale = 1.0f / fmaxf(sqrtf(s), EPSF);
    // raw copy (un-normalized), per reference: untouched rows keep raw values
    *(float4v*)(out_w + (size_t)row * NUM_FEATURES + lane * 4) = v;
    float4v nv = v * scale;
    short4v bv;
    bv.x = f2bf(nv.x); bv.y = f2bf(nv.y); bv.z = f2bf(nv.z); bv.w = f2bf(nv.w);
    *(short4v*)(wnb + (size_t)row * NUM_FEATURES + lane * 4) = bv;
}

// ---------------------------------------------------------------------------
// K3 (fused chain+update): one wave per batch index. Block i exits unless i is
// the first occurrence of its target ("head"); heads replay their duplicate
// chain in batch order in fp32, exactly matching the sequential reference
// (distinct targets are independent; only final row state is stored).
// Chain links found on the fly with a 64-lane ballot scan (no head/nxt arrays,
// no separate 1-block kernel serializing the GPU).
__global__ __launch_bounds__(64) void update_kernel(const float* __restrict__ xn,
                                                    const float* __restrict__ w_raw,
                                                    const int* __restrict__ tgt,
                                                    float* __restrict__ out_w) {
    __shared__ int t[BATCH];
    int i = blockIdx.x;
    int lane = threadIdx.x;
    for (int j = lane; j < BATCH; j += 64) t[j] = tgt[j];
    __syncthreads();
    int mine = t[i];
    bool dup = false;
    for (int j = lane; j < i; j += 64)
        if (t[j] == mine) { dup = true; break; }
    if (__any(dup)) return;  // not a chain head

    float4v row = *(const float4v*)(w_raw + (size_t)mine * NUM_FEATURES + lane * 4);
    int cur = i;
    while (cur >= 0) {
        const float4v xv = *(const float4v*)(xn + (size_t)cur * NUM_FEATURES + lane * 4);
        row = row * 0.5f + xv * 0.5f;
        float s = row.x * row.x + row.y * row.y + row.z * row.z + row.w * row.w;
        s = wave_reduce_sum(s);
        float scale = 1.0f / fmaxf(sqrtf(s), EPSF);
        row = row * scale;
        // find first j > cur with t[j] == mine (uniform across lanes)
        int nx = -1;
        for (int base = cur + 1; base < BATCH; base += 64) {
            int j = base + lane;
            bool m = (j < BATCH) && (t[j] == mine);
            unsigned long long mask = __ballot(m);
            if (mask) { nx = base + (int)__builtin_ctzll(mask); break; }
        }
        cur = nx;
    }
    *(float4v*)(out_w + (size_t)mine * NUM_FEATURES + lane * 4) = row;
}

// ---------------------------------------------------------------------------
// K4: predicts = (xn @ wnb^T) * 30. M=1024, N=100000, K=256. Write-dominated.
// 128x128 block tile, 4 waves in 2x2, each wave 64x64 via 16 mfma 16x16x32.
// MFMA operands are SWAPPED (mfma(b, a, acc)) so the C/D register quad holds
// 4 consecutive n columns -> float4 epilogue stores (16 x dwordx4 per wave,
// 1 KB per store instruction, full 64 B lines).
// K-loop: statically-indexed 2-deep register double buffer (loads of step s+1
// issue under step s's MFMAs; no runtime-indexed arrays -> no scratch).
// Grid: flat 6256 blocks with XCD-contiguous swizzle (6256 % 8 == 0 so the
// simple bijection applies): each XCD owns a contiguous by-chunk, and the 8
// M-blocks sharing one B-panel run back-to-back on the SAME XCD -> B panel
// reuse is served from that XCD's L2 instead of 8x from L3.
#define GRID_MX 8
#define GRID_NY 782
__global__ __launch_bounds__(256) void gemm_kernel(const short* __restrict__ xnb,
                                                   const short* __restrict__ wnb,
                                                   float* __restrict__ out) {
    int id = blockIdx.x;
    int orig = (id & 7) * (GRID_MX * GRID_NY / 8) + (id >> 3);
    int bx = orig & 7;   // M tile (orig % GRID_MX), fastest in orig space
    int by = orig >> 3;  // N tile (orig / GRID_MX)

    int tid = threadIdx.x;
    int lane = tid & 63;
    int wave = tid >> 6;
    int wm = wave & 1;
    int wn = wave >> 1;
    int m0 = bx * 128 + wm * 64;   // M = 1024 exactly divisible
    int n0 = by * 128 + wn * 64;   // N tail guarded at store
    int r16 = lane & 15;
    int quad = lane >> 4;

    float4v acc[4][4];
#pragma unroll
    for (int i = 0; i < 4; ++i)
#pragma unroll
        for (int j = 0; j < 4; ++j) acc[i][j] = (float4v){0.f, 0.f, 0.f, 0.f};

    const short* abase[4];
    const short* bbase[4];
#pragma unroll
    for (int i = 0; i < 4; ++i) {
        int m = m0 + i * 16 + r16;
        abase[i] = xnb + (size_t)m * NUM_FEATURES + quad * 8;
    }
#pragma unroll
    for (int j = 0; j < 4; ++j) {
        int n = n0 + j * 16 + r16;
        n = n < NUM_CLASSES ? n : (NUM_CLASSES - 1);  // tail rows clamped, discarded at store
        bbase[j] = wnb + (size_t)n * NUM_FEATURES + quad * 8;
    }

    short8 a[2][4], b[2][4];
#pragma unroll
    for (int i = 0; i < 4; ++i) a[0][i] = *(const short8*)(abase[i]);
#pragma unroll
    for (int j = 0; j < 4; ++j) b[0][j] = *(const short8*)(bbase[j]);

#pragma unroll
    for (int s = 0; s < 8; ++s) {  // K = 8 steps of 32 (fully unrolled: static buf idx)
        const int cur = s & 1;
        const int nxt = cur ^ 1;
        if (s < 7) {
            const int k0 = (s + 1) * 32;
#pragma unroll
            for (int i = 0; i < 4; ++i) a[nxt][i] = *(const short8*)(abase[i] + k0);
#pragma unroll
            for (int j = 0; j < 4; ++j) b[nxt][j] = *(const short8*)(bbase[j] + k0);
        }
#pragma unroll
        for (int i = 0; i < 4; ++i)
#pragma unroll
            for (int j = 0; j < 4; ++j)
                acc[i][j] = __builtin_amdgcn_mfma_f32_16x16x32_bf16(b[cur][j], a[cur][i],
                                                                    acc[i][j], 0, 0, 0);
    }

    // Swapped-operand C/D layout: col (lane&15) -> m-local, row (quad*4+r) -> n-local.
    // Each lane owns 4 consecutive n -> one dwordx4 store per (i,j).
#pragma unroll
    for (int j = 0; j < 4; ++j) {
        int nb = n0 + j * 16;
        if (nb < NUM_CLASSES) {  // 16-chunks are all-in or all-out (100000 % 16 == 0)
            int n = nb + quad * 4;
#pragma unroll
            for (int i = 0; i < 4; ++i) {
                int m = m0 + i * 16 + r16;
                float4v v = acc[i][j] * SCALARF;
                *(float4v*)(out + (size_t)m * NUM_CLASSES + n) = v;
            }
        }
    }
}

// ---------------------------------------------------------------------------
extern "C" void kernel_launch(void* const* d_in, const int* in_sizes, int n_in,
                              void* d_out, int out_size, void* d_ws, size_t ws_size,
                              hipStream_t stream) {
    const float* x = (const float*)d_in[0];     // [1024, 256] f32
    const int* tgt = (const int*)d_in[1];       // [1024] i32
    const float* w = (const float*)d_in[2];     // [100000, 256] f32

    float* out = (float*)d_out;
    float* out_pred = out;                                    // [1024, 100000]
    float* out_tgt = out + (size_t)BATCH * NUM_CLASSES;       // [1024] (as f32 values)
    float* out_w = out_tgt + BATCH;                           // [100000, 256]

    char* ws = (char*)d_ws;
    float* xn = (float*)ws;                                   // 1 MB fp32 x_norm
    short* xnb = (short*)(ws + (1 << 20));                    // 512 KB bf16 x_norm
    short* wnb = (short*)(ws + (1 << 20) + (1 << 19));        // 51.2 MB bf16 w_norm

    xnorm_kernel<<<BATCH, 64, 0, stream>>>(x, tgt, xn, xnb, out_tgt);
    wnorm_kernel<<<NUM_CLASSES / 4, 256, 0, stream>>>(w, wnb, out_w);
    update_kernel<<<BATCH, 64, 0, stream>>>(xn, w, tgt, out_w);
    gemm_kernel<<<GRID_MX * GRID_NY, 256, 0, stream>>>(xnb, wnb, out_pred);
}